// Round 1
// baseline (457.724 us; speedup 1.0000x reference)
//
#include <hip/hip_runtime.h>
#include <math.h>

#define BS 16
#define NA 2048
#define NB 2048
#define NK 64
#define NV 64
#define BN 64     // n-tile per block
#define TA 64     // a-tile per iteration
#define PAD 76    // padded LDS row stride in words (16B-aligned, spreads banks)
#define EPS 1e-8f

__global__ __launch_bounds__(256, 2)
void attn_fused_kernel(const float* __restrict__ key,    // [BS][NA][NK]
                       const float* __restrict__ query,  // [BS][NB][NK]
                       const float* __restrict__ value,  // [BS][NA][NV]
                       float* __restrict__ out,          // [BS][NV][NB]
                       float* __restrict__ wout)         // [BS][NA][NB]
{
    __shared__ float qT[NK][PAD];    // qT[k][n]  (Q transposed)
    __shared__ float k_s[TA][PAD];   // k_s[a][k]
    __shared__ float v_s[TA][PAD];   // v_s[a][v]
    __shared__ float w_s[TA][PAD];   // w_s[a][n]; aliased for reductions
    __shared__ float linv_s[BN];

    // reduction scratch aliased onto w_s (w_s is idle during both reductions)
    float (*red1)[17] = reinterpret_cast<float (*)[17]>(&w_s[0][0]);
    float (*red2)[17] = reinterpret_cast<float (*)[17]>(&w_s[32][0]);

    const int tid = threadIdx.x;
    const int b  = blockIdx.y;
    const int nt = blockIdx.x;
    const int n_base = nt * BN;

    const float* Kb = key   + (size_t)b * NA * NK;
    const float* Qb = query + (size_t)b * NB * NK;
    const float* Vb = value + (size_t)b * NA * NV;
    float* Wb = wout + (size_t)b * NA * NB;
    float* Ob = out  + (size_t)b * NV * NB;

    // thread tiling: 4a x 4n for S-compute; 4n x 4v for PV (n-group shared)
    const int a_grp = tid >> 4;        // 0..15
    const int n_grp = tid & 15;        // 0..15
    const int a0 = a_grp * 4;          // also v0 in PV phase
    const int n0 = n_grp * 4;
    const int v0 = a0;

    // ---- load Q tile transposed into LDS: qT[k][n] ----
    {
        const int n  = tid >> 2;       // 0..63
        const int kq = tid & 3;
        #pragma unroll
        for (int c = 0; c < 4; ++c) {
            const int k = (kq + 4 * c) * 4;   // 0..60
            float4 v = *reinterpret_cast<const float4*>(
                Qb + (size_t)(n_base + n) * NK + k);
            qT[k + 0][n] = v.x;
            qT[k + 1][n] = v.y;
            qT[k + 2][n] = v.z;
            qT[k + 3][n] = v.w;
        }
    }

    // =========== PASS A: l[n] = sum_a exp(S[a][n]) ===========
    float lpart[4] = {0.f, 0.f, 0.f, 0.f};

    for (int at = 0; at < NA; at += TA) {
        __syncthreads();
        // load K tile (row-major) into LDS
        {
            const int a  = tid >> 2;
            const int kq = tid & 3;
            #pragma unroll
            for (int c = 0; c < 4; ++c) {
                const int k = (kq + 4 * c) * 4;
                *reinterpret_cast<float4*>(&k_s[a][k]) =
                    *reinterpret_cast<const float4*>(Kb + (size_t)(at + a) * NK + k);
            }
        }
        __syncthreads();

        // S tile: sacc[i][j] = sum_k K[a0+i][k] * Q[n0+j][k]
        float sacc[4][4] = {};
        #pragma unroll
        for (int kq = 0; kq < 16; ++kq) {
            const int k = kq * 4;
            float kv[4][4];
            #pragma unroll
            for (int i = 0; i < 4; ++i)
                *reinterpret_cast<float4*>(kv[i]) =
                    *reinterpret_cast<const float4*>(&k_s[a0 + i][k]);
            #pragma unroll
            for (int kk = 0; kk < 4; ++kk) {
                float4 qv = *reinterpret_cast<const float4*>(&qT[k + kk][n0]);
                float q[4] = {qv.x, qv.y, qv.z, qv.w};
                #pragma unroll
                for (int i = 0; i < 4; ++i)
                    #pragma unroll
                    for (int j = 0; j < 4; ++j)
                        sacc[i][j] = fmaf(kv[i][kk], q[j], sacc[i][j]);
            }
        }
        #pragma unroll
        for (int i = 0; i < 4; ++i)
            #pragma unroll
            for (int j = 0; j < 4; ++j)
                lpart[j] += __expf(sacc[i][j] * 0.125f);
    }

    // reduce l across the 16 a-groups per n
    __syncthreads();
    #pragma unroll
    for (int j = 0; j < 4; ++j) red1[n0 + j][a_grp] = lpart[j];
    __syncthreads();
    if (tid < BN) {
        float s = 0.f;
        #pragma unroll
        for (int g = 0; g < 16; ++g) s += red1[tid][g];
        linv_s[tid] = 1.0f / s;
    }

    // =========== PASS B: w = exp(S)/l, write w, accumulate PV ===========
    float acc[4][4] = {};   // [jn][jv]

    for (int at = 0; at < NA; at += TA) {
        __syncthreads();
        // load K tile and V tile
        {
            const int a  = tid >> 2;
            const int kq = tid & 3;
            #pragma unroll
            for (int c = 0; c < 4; ++c) {
                const int k = (kq + 4 * c) * 4;
                *reinterpret_cast<float4*>(&k_s[a][k]) =
                    *reinterpret_cast<const float4*>(Kb + (size_t)(at + a) * NK + k);
                *reinterpret_cast<float4*>(&v_s[a][k]) =
                    *reinterpret_cast<const float4*>(Vb + (size_t)(at + a) * NV + k);
            }
        }
        __syncthreads();

        float sacc[4][4] = {};
        #pragma unroll
        for (int kq = 0; kq < 16; ++kq) {
            const int k = kq * 4;
            float kv[4][4];
            #pragma unroll
            for (int i = 0; i < 4; ++i)
                *reinterpret_cast<float4*>(kv[i]) =
                    *reinterpret_cast<const float4*>(&k_s[a0 + i][k]);
            #pragma unroll
            for (int kk = 0; kk < 4; ++kk) {
                float4 qv = *reinterpret_cast<const float4*>(&qT[k + kk][n0]);
                float q[4] = {qv.x, qv.y, qv.z, qv.w};
                #pragma unroll
                for (int i = 0; i < 4; ++i)
                    #pragma unroll
                    for (int j = 0; j < 4; ++j)
                        sacc[i][j] = fmaf(kv[i][kk], q[j], sacc[i][j]);
            }
        }

        // w = exp(S)/l ; write to global (from regs) and LDS (for PV)
        #pragma unroll
        for (int i = 0; i < 4; ++i) {
            float4 wv;
            wv.x = __expf(sacc[i][0] * 0.125f) * linv_s[n0 + 0];
            wv.y = __expf(sacc[i][1] * 0.125f) * linv_s[n0 + 1];
            wv.z = __expf(sacc[i][2] * 0.125f) * linv_s[n0 + 2];
            wv.w = __expf(sacc[i][3] * 0.125f) * linv_s[n0 + 3];
            *reinterpret_cast<float4*>(Wb + (size_t)(at + a0 + i) * NB + n_base + n0) = wv;
            *reinterpret_cast<float4*>(&w_s[a0 + i][n0]) = wv;
        }
        __syncthreads();

        // PV: acc[jn][jv] += w_s[a][n0+jn] * v_s[a][v0+jv]
        #pragma unroll 4
        for (int a = 0; a < TA; ++a) {
            float4 wv = *reinterpret_cast<const float4*>(&w_s[a][n0]);
            float4 vv = *reinterpret_cast<const float4*>(&v_s[a][v0]);
            float wj[4] = {wv.x, wv.y, wv.z, wv.w};
            float vj[4] = {vv.x, vv.y, vv.z, vv.w};
            #pragma unroll
            for (int jn = 0; jn < 4; ++jn)
                #pragma unroll
                for (int jv = 0; jv < 4; ++jv)
                    acc[jn][jv] = fmaf(wj[jn], vj[jv], acc[jn][jv]);
        }
    }

    // =========== epilogue: per-(b,n) normalize over v, write out^T ===========
    __syncthreads();
    {
        #pragma unroll
        for (int jn = 0; jn < 4; ++jn) {
            float s1 = 0.f, s2 = 0.f;
            #pragma unroll
            for (int jv = 0; jv < 4; ++jv) {
                float x = acc[jn][jv];
                s1 += x;
                s2 = fmaf(x, x, s2);
            }
            red1[n0 + jn][a_grp] = s1;
            red2[n0 + jn][a_grp] = s2;
        }
    }
    __syncthreads();
    if (tid < BN) {
        float t1 = 0.f, t2 = 0.f;
        #pragma unroll
        for (int g = 0; g < 16; ++g) { t1 += red1[tid][g]; t2 += red2[tid][g]; }
        const float mu  = t1 * (1.0f / 64.0f);
        float var = (t2 - 64.0f * mu * mu) * (1.0f / 63.0f);
        var = fmaxf(var, 0.0f);
        red1[tid][16] = mu;
        red2[tid][16] = 1.0f / (sqrtf(var) + EPS);
    }
    __syncthreads();
    {
        float mu[4], is[4];
        #pragma unroll
        for (int jn = 0; jn < 4; ++jn) {
            mu[jn] = red1[n0 + jn][16];
            is[jn] = red2[n0 + jn][16];
        }
        #pragma unroll
        for (int jv = 0; jv < 4; ++jv) {
            float4 o;
            o.x = (acc[0][jv] - mu[0]) * is[0];
            o.y = (acc[1][jv] - mu[1]) * is[1];
            o.z = (acc[2][jv] - mu[2]) * is[2];
            o.w = (acc[3][jv] - mu[3]) * is[3];
            *reinterpret_cast<float4*>(Ob + (size_t)(v0 + jv) * NB + n_base + n0) = o;
        }
    }
}

extern "C" void kernel_launch(void* const* d_in, const int* in_sizes, int n_in,
                              void* d_out, int out_size, void* d_ws, size_t ws_size,
                              hipStream_t stream) {
    const float* key   = (const float*)d_in[0];
    const float* query = (const float*)d_in[1];
    const float* value = (const float*)d_in[2];
    float* out  = (float*)d_out;                       // [BS][NV][NB]
    float* wout = out + (size_t)BS * NV * NB;          // [BS][NA][NB]

    dim3 grid(NB / BN, BS);
    attn_fused_kernel<<<grid, 256, 0, stream>>>(key, query, value, out, wout);
}

// Round 2
// 152.354 us; speedup vs baseline: 3.0044x; 3.0044x over previous
//
#include <hip/hip_runtime.h>
#include <math.h>

#define BS 16
#define NA 2048
#define NB 2048
#define NK 64
#define NV 64
#define BN 64     // n-tile per block
#define TA 64     // a-tile per iteration
#define SQ 72     // bf16 LDS row stride (elements): 144B -> 2-way banks (free)
#define OSTR 68   // f32 out_lds row stride (16B-aligned rows)
#define EPS 1e-8f

typedef float        f32x4  __attribute__((ext_vector_type(4)));
typedef __bf16       bf16x8 __attribute__((ext_vector_type(8)));
typedef short        s16x8  __attribute__((ext_vector_type(8)));
typedef unsigned int u32x4  __attribute__((ext_vector_type(4)));
typedef unsigned short u16x8 __attribute__((ext_vector_type(8)));

// ---- MFMA wrapper: prefer bf16-vector signature, SFINAE-fallback to short8 ----
template <typename V>
__device__ __forceinline__ auto mfma_impl(V a, V b, f32x4 c, int)
    -> decltype(__builtin_amdgcn_mfma_f32_16x16x32_bf16(a, b, c, 0, 0, 0)) {
    return __builtin_amdgcn_mfma_f32_16x16x32_bf16(a, b, c, 0, 0, 0);
}
template <typename V>
__device__ __forceinline__ auto mfma_impl(V a, V b, f32x4 c, long)
    -> decltype(__builtin_amdgcn_mfma_f32_16x16x32_bf16(
           __builtin_bit_cast(s16x8, a), __builtin_bit_cast(s16x8, b), c, 0, 0, 0)) {
    return __builtin_amdgcn_mfma_f32_16x16x32_bf16(
        __builtin_bit_cast(s16x8, a), __builtin_bit_cast(s16x8, b), c, 0, 0, 0);
}
__device__ __forceinline__ f32x4 mfma_bf16(u32x4 a, u32x4 b, f32x4 c) {
    bf16x8 av = __builtin_bit_cast(bf16x8, a);
    bf16x8 bv = __builtin_bit_cast(bf16x8, b);
    return mfma_impl(av, bv, c, 0);
}

// manual RNE f32 -> bf16 (inputs finite; avoids __bf16 conversion questions)
__device__ __forceinline__ unsigned short f2bf(float x) {
    unsigned u = __builtin_bit_cast(unsigned, x);
    unsigned r = (u + 0x7FFFu + ((u >> 16) & 1u)) >> 16;
    return (unsigned short)r;
}
__device__ __forceinline__ u16x8 pk8(f32x4 a, f32x4 b) {
    u16x8 p;
    p[0] = f2bf(a[0]); p[1] = f2bf(a[1]); p[2] = f2bf(a[2]); p[3] = f2bf(a[3]);
    p[4] = f2bf(b[0]); p[5] = f2bf(b[1]); p[6] = f2bf(b[2]); p[7] = f2bf(b[3]);
    return p;
}
__device__ __forceinline__ f32x4 ldg4(const float* p) { return *(const f32x4*)p; }

// LDS layout (bytes):
//   Qs  bf16[64][SQ]   @ 0      (9216)
//   Ks  bf16[64][SQ]   @ 9216   (9216)
//   Vts bf16[64][SQ]   @ 18432  (9216)   (V transposed: Vts[v][a])
//   Es  bf16[64][SQ]   @ 27648  (9216)   (P transposed: Es[n][a])
//   linv f32[64]       @ 36864  (256)
//   lred f32[4][64]    @ 37120  (1024)
//   out_lds f32[64][OSTR] aliases Vts+Es @ 18432 (17408 <= 18432)
#define SMEM_BYTES 38144

__global__ __launch_bounds__(256, 2)
void attn_mfma_kernel(const float* __restrict__ key,    // [BS][NA][NK]
                      const float* __restrict__ query,  // [BS][NB][NK]
                      const float* __restrict__ value,  // [BS][NA][NV]
                      float* __restrict__ out,          // [BS][NV][NB]
                      float* __restrict__ wout)         // [BS][NA][NB]
{
    __shared__ __align__(16) char smem[SMEM_BYTES];
    unsigned short* Qs   = (unsigned short*)(smem);
    unsigned short* Ks   = (unsigned short*)(smem + 9216);
    unsigned short* Vts  = (unsigned short*)(smem + 18432);
    unsigned short* Es   = (unsigned short*)(smem + 27648);
    float*          linv_s = (float*)(smem + 36864);
    float (*lred)[64] = (float (*)[64])(smem + 37120);
    float*          outl = (float*)(smem + 18432);

    const int tid  = threadIdx.x;
    const int wave = tid >> 6;
    const int lane = tid & 63;
    const int lr   = lane & 15;   // MFMA row/col lane index
    const int lg   = lane >> 4;   // MFMA k-group / reg-row group
    const int b    = blockIdx.y;
    const int nb   = blockIdx.x * BN;
    const int aw   = wave * 16;   // wave's a-subtile base (S phase)

    const float* Kb = key   + (size_t)b * NA * NK;
    const float* Qb = query + (size_t)b * NB * NK;
    const float* Vb = value + (size_t)b * NA * NV;
    float* Wb = wout + (size_t)b * NA * NB;
    float* Ob = out  + (size_t)b * NV * NB;

    // ---- stage Q tile (bf16, row-major [n][k]) once ----
    {
        const int r = tid >> 2;            // n row 0..63
        const int c = (tid & 3) * 16;      // col chunk
        const float* src = Qb + (size_t)(nb + r) * NK + c;
        f32x4 q0 = ldg4(src), q1 = ldg4(src + 4), q2 = ldg4(src + 8), q3 = ldg4(src + 12);
        *(u16x8*)&Qs[r * SQ + c]     = pk8(q0, q1);
        *(u16x8*)&Qs[r * SQ + c + 8] = pk8(q2, q3);
    }

    // =========== PASS A: l[n] = sum_a exp(S[n][a]) ===========
    float lacc[4][4] = {};   // [t = n-subtile][r]; lane's a-column = aw+lr

    for (int at = 0; at < NA; at += TA) {
        // stage K tile (bf16, row-major [a][k])
        {
            const int r = tid >> 2;
            const int c = (tid & 3) * 16;
            const float* src = Kb + (size_t)(at + r) * NK + c;
            f32x4 k0 = ldg4(src), k1 = ldg4(src + 4), k2 = ldg4(src + 8), k3 = ldg4(src + 12);
            *(u16x8*)&Ks[r * SQ + c]     = pk8(k0, k1);
            *(u16x8*)&Ks[r * SQ + c + 8] = pk8(k2, k3);
        }
        __syncthreads();

        // B-frags: col a = aw+lr, k-chunks
        u32x4 bf0 = *(const u32x4*)&Ks[(aw + lr) * SQ + (lg * 8)];
        u32x4 bf1 = *(const u32x4*)&Ks[(aw + lr) * SQ + (32 + lg * 8)];
        #pragma unroll
        for (int t = 0; t < 4; ++t) {
            f32x4 acc = {0.f, 0.f, 0.f, 0.f};
            u32x4 af0 = *(const u32x4*)&Qs[(t * 16 + lr) * SQ + (lg * 8)];
            u32x4 af1 = *(const u32x4*)&Qs[(t * 16 + lr) * SQ + (32 + lg * 8)];
            acc = mfma_bf16(af0, bf0, acc);
            acc = mfma_bf16(af1, bf1, acc);
            #pragma unroll
            for (int r = 0; r < 4; ++r)
                lacc[t][r] += __expf(acc[r] * 0.125f);
        }
        __syncthreads();
    }

    // reduce l over the 16 a-lanes, then over 4 waves
    #pragma unroll
    for (int t = 0; t < 4; ++t)
        #pragma unroll
        for (int r = 0; r < 4; ++r) {
            float v = lacc[t][r];
            v += __shfl_xor(v, 1);
            v += __shfl_xor(v, 2);
            v += __shfl_xor(v, 4);
            v += __shfl_xor(v, 8);
            lacc[t][r] = v;
        }
    if (lr == 0) {
        #pragma unroll
        for (int t = 0; t < 4; ++t)
            #pragma unroll
            for (int r = 0; r < 4; ++r)
                lred[wave][t * 16 + lg * 4 + r] = lacc[t][r];
    }
    __syncthreads();
    if (tid < 64) {
        float s = lred[0][tid] + lred[1][tid] + lred[2][tid] + lred[3][tid];
        linv_s[tid] = 1.0f / s;
    }
    __syncthreads();
    // per-lane linv for its 16 n indices (broadcast b128 reads)
    f32x4 linv[4];
    #pragma unroll
    for (int t = 0; t < 4; ++t)
        linv[t] = *(const f32x4*)&linv_s[t * 16 + lg * 4];

    // =========== PASS B: w = e/l (store), PV via MFMA ===========
    f32x4 pacc[4] = {{0.f,0.f,0.f,0.f},{0.f,0.f,0.f,0.f},{0.f,0.f,0.f,0.f},{0.f,0.f,0.f,0.f}};

    for (int at = 0; at < NA; at += TA) {
        // stage K tile
        {
            const int r = tid >> 2;
            const int c = (tid & 3) * 16;
            const float* src = Kb + (size_t)(at + r) * NK + c;
            f32x4 k0 = ldg4(src), k1 = ldg4(src + 4), k2 = ldg4(src + 8), k3 = ldg4(src + 12);
            *(u16x8*)&Ks[r * SQ + c]     = pk8(k0, k1);
            *(u16x8*)&Ks[r * SQ + c + 8] = pk8(k2, k3);
        }
        // stage V transposed (Vts[v][a]), packed pair writes
        {
            const int ap = (tid & 31) * 2;     // a-pair base
            const int q  = tid >> 5;           // 0..7 -> v block of 8
            const float* v0p = Vb + (size_t)(at + ap) * NV + q * 8;
            const float* v1p = v0p + NV;
            f32x4 a0 = ldg4(v0p), a1 = ldg4(v0p + 4);
            f32x4 b0 = ldg4(v1p), b1 = ldg4(v1p + 4);
            #pragma unroll
            for (int j = 0; j < 4; ++j) {
                unsigned int w0 = (unsigned)f2bf(a0[j]) | ((unsigned)f2bf(b0[j]) << 16);
                *(unsigned int*)&Vts[(q * 8 + j) * SQ + ap] = w0;
                unsigned int w1 = (unsigned)f2bf(a1[j]) | ((unsigned)f2bf(b1[j]) << 16);
                *(unsigned int*)&Vts[(q * 8 + 4 + j) * SQ + ap] = w1;
            }
        }
        __syncthreads();

        // ---- S phase: D[n][a], waves split a ----
        u32x4 bf0 = *(const u32x4*)&Ks[(aw + lr) * SQ + (lg * 8)];
        u32x4 bf1 = *(const u32x4*)&Ks[(aw + lr) * SQ + (32 + lg * 8)];
        #pragma unroll
        for (int t = 0; t < 4; ++t) {
            f32x4 acc = {0.f, 0.f, 0.f, 0.f};
            u32x4 af0 = *(const u32x4*)&Qs[(t * 16 + lr) * SQ + (lg * 8)];
            u32x4 af1 = *(const u32x4*)&Qs[(t * 16 + lr) * SQ + (32 + lg * 8)];
            acc = mfma_bf16(af0, bf0, acc);
            acc = mfma_bf16(af1, bf1, acc);
            f32x4 wv;
            #pragma unroll
            for (int r = 0; r < 4; ++r)
                wv[r] = __expf(acc[r] * 0.125f) * linv[t][r];
            // w store: row a = at+aw+lr, 4 consecutive n
            *(f32x4*)(Wb + (size_t)(at + aw + lr) * NB + nb + t * 16 + lg * 4) = wv;
            // P^T to LDS: Es[n][a] bf16
            #pragma unroll
            for (int r = 0; r < 4; ++r)
                Es[(t * 16 + lg * 4 + r) * SQ + (aw + lr)] = f2bf(wv[r]);
        }
        __syncthreads();

        // ---- PV phase: D[n][v], waves split n; A = Es[n][a], B = Vts[v][a] ----
        u32x4 paf0 = *(const u32x4*)&Es[(wave * 16 + lr) * SQ + (lg * 8)];
        u32x4 paf1 = *(const u32x4*)&Es[(wave * 16 + lr) * SQ + (32 + lg * 8)];
        #pragma unroll
        for (int t = 0; t < 4; ++t) {
            u32x4 vb0 = *(const u32x4*)&Vts[(t * 16 + lr) * SQ + (lg * 8)];
            u32x4 vb1 = *(const u32x4*)&Vts[(t * 16 + lr) * SQ + (32 + lg * 8)];
            pacc[t] = mfma_bf16(paf0, vb0, pacc[t]);
            pacc[t] = mfma_bf16(paf1, vb1, pacc[t]);
        }
        __syncthreads();
    }

    // =========== epilogue: normalize over v (ddof=1), transpose, store ===========
    // lane holds vals[n][v] at n = wave*16 + lg*4 + r, v = t*16 + lr
    float mu[4], istd[4];
    #pragma unroll
    for (int r = 0; r < 4; ++r) {
        float s1 = 0.f, s2 = 0.f;
        #pragma unroll
        for (int t = 0; t < 4; ++t) { float x = pacc[t][r]; s1 += x; s2 = fmaf(x, x, s2); }
        s1 += __shfl_xor(s1, 1); s2 += __shfl_xor(s2, 1);
        s1 += __shfl_xor(s1, 2); s2 += __shfl_xor(s2, 2);
        s1 += __shfl_xor(s1, 4); s2 += __shfl_xor(s2, 4);
        s1 += __shfl_xor(s1, 8); s2 += __shfl_xor(s2, 8);
        float m = s1 * (1.0f / 64.0f);
        float var = (s2 - 64.0f * m * m) * (1.0f / 63.0f);
        var = fmaxf(var, 0.0f);
        mu[r] = m;
        istd[r] = 1.0f / (sqrtf(var) + EPS);
    }
    // write normalized values transposed into LDS (aliases Vts/Es; PV done)
    #pragma unroll
    for (int t = 0; t < 4; ++t)
        #pragma unroll
        for (int r = 0; r < 4; ++r)
            outl[(t * 16 + lr) * OSTR + wave * 16 + lg * 4 + r] =
                (pacc[t][r] - mu[r]) * istd[r];
    __syncthreads();
    // coalesced out stores: out[v][n]
    {
        const int v = tid >> 2;
        const int c = (tid & 3) * 16;
        float* dst = Ob + (size_t)v * NB + nb + c;
        const float* srcr = &outl[v * OSTR + c];
        #pragma unroll
        for (int j = 0; j < 4; ++j)
            *(f32x4*)(dst + 4 * j) = *(const f32x4*)(srcr + 4 * j);
    }
}

extern "C" void kernel_launch(void* const* d_in, const int* in_sizes, int n_in,
                              void* d_out, int out_size, void* d_ws, size_t ws_size,
                              hipStream_t stream) {
    const float* key   = (const float*)d_in[0];
    const float* query = (const float*)d_in[1];
    const float* value = (const float*)d_in[2];
    float* out  = (float*)d_out;                   // [BS][NV][NB]
    float* wout = out + (size_t)BS * NV * NB;      // [BS][NA][NB]

    dim3 grid(NB / BN, BS);
    attn_mfma_kernel<<<grid, 256, 0, stream>>>(key, query, value, out, wout);
}